// Round 7
// baseline (512.835 us; speedup 1.0000x reference)
//
#include <hip/hip_runtime.h>

#define BB 8
#define NN 2048
#define CC 128
#define KMAX 32
#define NEG 0.2f
#define CH 8
#define CHSZ (NN / CH)   // 256
#define CPAD 260         // chunk stride in LDS: (260*c+jj)%32 = (4c+jj)%32 -> 8 distinct banks

// Map f32 to a u32 whose unsigned order == float order (handles negatives).
__device__ __forceinline__ unsigned int f2key(float f) {
  unsigned int b = __float_as_uint(f);
  return (b & 0x80000000u) ? ~b : (b | 0x80000000u);
}

// np-exact f32 squared norm: fl(fl(x^2+y^2)+z^2), no FMA contraction.
__device__ __forceinline__ float sq3(float x, float y, float z) {
  return __fadd_rn(__fadd_rn(__fmul_rn(x, x), __fmul_rn(y, y)), __fmul_rn(z, z));
}

// np-exact f32 distance key: d2 = fl( fl(sq_i+sq_j) - fl(2*dot) ),
// dot = fma(a2,b2, fma(a1,b1, round(a0*b0)))  (BLAS K-ascending FMA chain).
__device__ __forceinline__ float d2np(float px, float py, float pz, float sqq,
                                      float qx, float qy, float qz, float sqj) {
  float dot = __fmaf_rn(pz, qz, __fmaf_rn(py, qy, __fmul_rn(px, qx)));
  return __fsub_rn(__fadd_rn(sqq, sqj), __fmul_rn(2.0f, dot));
}

// ---------------------------------------------------------------------------
// K1a: KNN phase 1 — chunked candidate selection with np-bit-exact f32 keys.
// Identical selection semantics to the R6 passing kernel; ONLY the LDS layout
// changed to padded SoA (spx[c*CPAD+jj]) so the 8 chunk-lanes of a query hit
// 8 distinct banks (queries broadcast) — kills the 2.9e7 8-way conflicts.
// Block = 256 threads = 32 queries x 8 chunks of one batch. Grid = 512.
// ---------------------------------------------------------------------------
__global__ __launch_bounds__(256) void knn_p1(const float* __restrict__ pos,
                                              unsigned short* __restrict__ cand) {
  __shared__ float spx[CH * CPAD], spy[CH * CPAD], spz[CH * CPAD], ssq[CH * CPAD];
  int b = blockIdx.x >> 6;                       // 64 blocks per batch
  int qbase = (blockIdx.x & 63) * 32;
  const float* pb = pos + (size_t)b * NN * 3;
  for (int t = threadIdx.x; t < NN; t += 256) {
    int a = ((t >> 8) * CPAD) + (t & 255);       // padded SoA address of point t
    float x = pb[t * 3 + 0];
    float y = pb[t * 3 + 1];
    float z = pb[t * 3 + 2];
    spx[a] = x; spy[a] = y; spz[a] = z;
    ssq[a] = sq3(x, y, z);                       // same math/values as R6
  }
  __syncthreads();

  int q = qbase + (threadIdx.x >> 3);
  int c = threadIdx.x & 7;
  int qa = ((q >> 8) * CPAD) + (q & 255);
  float px = spx[qa], py = spy[qa], pz = spz[qa];
  float sqq = ssq[qa];

  unsigned int ak[KMAX];
  int ai[KMAX];
#pragma unroll
  for (int k = 0; k < KMAX; ++k) { ak[k] = 0xFFFFFFFFu; ai[k] = 0; }

  int abase = c * CPAD;
  int j0 = c * CHSZ;
  for (int jj = 0; jj < CHSZ; ++jj) {            // j-ascending within chunk
    int a = abase + jj;
    int j = j0 + jj;                             // true global index
    float d2 = d2np(px, py, pz, sqq, spx[a], spy[a], spz[a], ssq[a]);
    unsigned int key = f2key(d2);
    if (j == q) key = 0xFFFFFFFFu;               // exclude self (+1e10 diag)
    if (key < ak[KMAX - 1]) {                    // strict: stable ties -> lower j
#pragma unroll
      for (int k = KMAX - 1; k >= 1; --k) {
        bool ck  = key < ak[k];
        bool ckm = key < ak[k - 1];
        unsigned int tk = ckm ? ak[k - 1] : key;
        int          ti = ckm ? ai[k - 1] : j;
        ak[k] = ck ? tk : ak[k];
        ai[k] = ck ? ti : ai[k];
      }
      bool c0 = key < ak[0];
      ak[0] = c0 ? key : ak[0];
      ai[0] = c0 ? j : ai[0];
    }
  }

  unsigned short* oc = cand + (((size_t)(b * NN + q)) * CH + c) * KMAX;
#pragma unroll
  for (int k = 0; k < KMAX; ++k) oc[k] = (unsigned short)ai[k];
}

// ---------------------------------------------------------------------------
// K1b: KNN phase 2 — stable merge of the 8 chunk lists, same f32 keys.
// (verbatim from the R6 passing kernel)
// ---------------------------------------------------------------------------
__global__ __launch_bounds__(64) void knn_p2(const float* __restrict__ pos,
                                             const unsigned short* __restrict__ cand,
                                             int* __restrict__ nbr) {
  __shared__ float sp[NN * 3];
  __shared__ float ssq[NN];
  int b = blockIdx.x >> 5;                       // 32 blocks per batch
  int q = (blockIdx.x & 31) * 64 + threadIdx.x;
  const float* pb = pos + (size_t)b * NN * 3;
  for (int t = threadIdx.x; t < NN * 3; t += 64) sp[t] = pb[t];
  __syncthreads();
  for (int t = threadIdx.x; t < NN; t += 64)
    ssq[t] = sq3(sp[t * 3 + 0], sp[t * 3 + 1], sp[t * 3 + 2]);
  __syncthreads();

  float px = sp[q * 3 + 0], py = sp[q * 3 + 1], pz = sp[q * 3 + 2];
  float sqq = ssq[q];

  unsigned int ak[KMAX];
  int ai[KMAX];
#pragma unroll
  for (int k = 0; k < KMAX; ++k) { ak[k] = 0xFFFFFFFFu; ai[k] = 0; }

  const unsigned short* cq = cand + ((size_t)(b * NN + q)) * (CH * KMAX);
  for (int u = 0; u < CH * KMAX; ++u) {
    int j = (int)cq[u];
    float d2 = d2np(px, py, pz, sqq,
                    sp[j * 3 + 0], sp[j * 3 + 1], sp[j * 3 + 2], ssq[j]);
    unsigned int key = f2key(d2);
    if (j == q) key = 0xFFFFFFFFu;
    if (key < ak[KMAX - 1]) {
#pragma unroll
      for (int k = KMAX - 1; k >= 1; --k) {
        bool ck  = key < ak[k];
        bool ckm = key < ak[k - 1];
        unsigned int tk = ckm ? ak[k - 1] : key;
        int          ti = ckm ? ai[k - 1] : j;
        ak[k] = ck ? tk : ak[k];
        ai[k] = ck ? ti : ai[k];
      }
      bool c0 = key < ak[0];
      ak[0] = c0 ? key : ak[0];
      ai[0] = c0 ? j : ai[0];
    }
  }

  int* onb = nbr + ((size_t)(b * NN + q)) * KMAX;
#pragma unroll
  for (int k = 0; k < KMAX; ++k) onb[k] = ai[k];
}

// ---------------------------------------------------------------------------
// K2: f32 tiled GEMM  out[M][128] = concat(A1[:,0:K1], A2[:,0:K-K1]) @ W
// blockIdx.z selects among up to 6 weight matrices and output slices.
// (verbatim from the R6 passing kernel)
// ---------------------------------------------------------------------------
__global__ __launch_bounds__(256) void gemm_kernel(
    const float* __restrict__ A1, int lda1, int K1,
    const float* __restrict__ A2, int lda2, int K,
    const float* __restrict__ Wa, const float* __restrict__ Wb,
    const float* __restrict__ Wc, const float* __restrict__ bias,
    float* __restrict__ outbase, int applyLeaky) {
  __shared__ float At[8][64];
  __shared__ float Wt[8][CC];

  int z = blockIdx.z;
  const float* W = (z < 2) ? (Wa + (size_t)z * CC * CC)
                 : (z < 4) ? (Wb + (size_t)(z - 2) * CC * CC)
                           : (Wc + (size_t)(z - 4) * CC * CC);
  float* out = outbase + (size_t)z * ((size_t)BB * NN * CC);

  int m0 = blockIdx.x * 64;
  int tid = threadIdx.x;
  int cg = tid & 31;
  int rg = tid >> 5;

  float acc[8][4];
#pragma unroll
  for (int r = 0; r < 8; ++r)
#pragma unroll
    for (int q = 0; q < 4; ++q) acc[r][q] = 0.f;

  int ksteps = (K + 7) >> 3;
  for (int ks = 0; ks < ksteps; ++ks) {
    int k0 = ks << 3;
    __syncthreads();
    {
      int f = tid * 2;
      int m = f >> 3;
      int kk = f & 7;
      int gm = m0 + m;
#pragma unroll
      for (int u = 0; u < 2; ++u) {
        int k = k0 + kk + u;
        float v = 0.f;
        if (k < K1) v = A1[(size_t)gm * lda1 + k];
        else if (k < K) v = A2[(size_t)gm * lda2 + (k - K1)];
        At[kk + u][m] = v;
      }
    }
    {
      int kk = tid >> 5;
      int c = (tid & 31) * 4;
      int k = k0 + kk;
      float4 w = make_float4(0.f, 0.f, 0.f, 0.f);
      if (k < K) w = *(const float4*)(W + (size_t)k * CC + c);
      *(float4*)(&Wt[kk][c]) = w;
    }
    __syncthreads();
#pragma unroll
    for (int kk = 0; kk < 8; ++kk) {
      float4 a0 = *(const float4*)(&At[kk][rg * 8]);
      float4 a1 = *(const float4*)(&At[kk][rg * 8 + 4]);
      float4 w = *(const float4*)(&Wt[kk][cg * 4]);
      float a[8] = {a0.x, a0.y, a0.z, a0.w, a1.x, a1.y, a1.z, a1.w};
#pragma unroll
      for (int r = 0; r < 8; ++r) {
        acc[r][0] += a[r] * w.x;
        acc[r][1] += a[r] * w.y;
        acc[r][2] += a[r] * w.z;
        acc[r][3] += a[r] * w.w;
      }
    }
  }

#pragma unroll
  for (int r = 0; r < 8; ++r) {
    int m = m0 + rg * 8 + r;
#pragma unroll
    for (int q = 0; q < 4; ++q) {
      int c = cg * 4 + q;
      float v = acc[r][q];
      if (bias) v += bias[c];
      if (applyLeaky) v = v > 0.f ? v : NEG * v;
      out[(size_t)m * CC + c] = v;
    }
  }
}

// ---------------------------------------------------------------------------
// K3: fused attention — both dilations in one launch, one h read/write.
// Accumulation chain matches R6 exactly: (h_in + a_d1) + a_d2.
// Block = 128 threads = channels of one point.
// ---------------------------------------------------------------------------
__global__ __launch_bounds__(128) void attn2_kernel(
    const float* __restrict__ pos, const int* __restrict__ nbr,
    const float* __restrict__ s0, const float* __restrict__ v0,
    const float* __restrict__ t0,
    const float* __restrict__ s1, const float* __restrict__ v1,
    const float* __restrict__ t1,
    const float* __restrict__ Wpos, const float* __restrict__ bpos,
    float* __restrict__ h) {
  int bn = blockIdx.x;
  int b = bn >> 11;
  int n = bn & (NN - 1);
  int c = threadIdx.x;

  const float* pb = pos + (size_t)b * NN * 3;
  float pix = pb[n * 3 + 0], piy = pb[n * 3 + 1], piz = pb[n * 3 + 2];
  const int* nb = nbr + (size_t)bn * KMAX;

  float ht = h[(size_t)bn * CC + c];             // h_in (Wg output)

#pragma unroll
  for (int l = 0; l < 2; ++l) {
    int dil = l + 1;
    const float* s = l ? s1 : s0;
    const float* v = l ? v1 : v0;
    const float* t = l ? t1 : t0;
    const float* Wp = Wpos + (size_t)l * 3 * CC;
    float w0 = Wp[c], w1 = Wp[CC + c], w2 = Wp[2 * CC + c];
    float bp = bpos[(size_t)l * CC + c];
    float tc = t[(size_t)bn * CC + c];

    float alpha[17], del[17];
    float mx = -1e30f;
#pragma unroll
    for (int j = 0; j < 17; ++j) {
      int idx = (j < 16) ? nb[j * dil] : n;
      float dx = pix - pb[idx * 3 + 0];
      float dy = piy - pb[idx * 3 + 1];
      float dz = piz - pb[idx * 3 + 2];
      float d = dx * w0 + dy * w1 + dz * w2 + bp;
      del[j] = d;
      float sc = s[((size_t)(b * NN + idx)) * CC + c];
      float a = tc - sc + d;
      alpha[j] = a;
      mx = fmaxf(mx, a);
    }
    float sum = 0.f;
#pragma unroll
    for (int j = 0; j < 17; ++j) {
      float w = expf(alpha[j] - mx);
      alpha[j] = w;
      sum += w;
    }
    float inv = 1.f / sum;
    float hc = 0.f;
#pragma unroll
    for (int j = 0; j < 17; ++j) {
      int idx = (j < 16) ? nb[j * dil] : n;
      float vc = v[((size_t)(b * NN + idx)) * CC + c];
      hc += alpha[j] * (vc + del[j]);
    }
    ht += hc * inv;                              // same chain as R6's h += per layer
  }

  h[(size_t)bn * CC + c] = ht;
}

// ---------------------------------------------------------------------------
// K5: out[m][0..2] = g[m] @ W2 + b2 + pos[m].  One wave per point.
// (verbatim from the R6 passing kernel)
// ---------------------------------------------------------------------------
__global__ __launch_bounds__(64) void final_kernel(
    const float* __restrict__ g, const float* __restrict__ W2,
    const float* __restrict__ b2, const float* __restrict__ pos,
    float* __restrict__ out) {
  int m = blockIdx.x;
  int k = threadIdx.x;
  float g0 = g[(size_t)m * CC + k];
  float g1 = g[(size_t)m * CC + 64 + k];
  float p0 = g0 * W2[k * 3 + 0] + g1 * W2[(k + 64) * 3 + 0];
  float p1 = g0 * W2[k * 3 + 1] + g1 * W2[(k + 64) * 3 + 1];
  float p2 = g0 * W2[k * 3 + 2] + g1 * W2[(k + 64) * 3 + 2];
#pragma unroll
  for (int off = 32; off >= 1; off >>= 1) {
    p0 += __shfl_down(p0, off);
    p1 += __shfl_down(p1, off);
    p2 += __shfl_down(p2, off);
  }
  if (k == 0) {
    out[m * 3 + 0] = p0 + b2[0] + pos[m * 3 + 0];
    out[m * 3 + 1] = p1 + b2[1] + pos[m * 3 + 1];
    out[m * 3 + 2] = p2 + b2[2] + pos[m * 3 + 2];
  }
}

extern "C" void kernel_launch(void* const* d_in, const int* in_sizes, int n_in,
                              void* d_out, int out_size, void* d_ws, size_t ws_size,
                              hipStream_t stream) {
  const float* x     = (const float*)d_in[0];
  const float* pos   = (const float*)d_in[1];
  const float* W_lin = (const float*)d_in[2];
  const float* W_src = (const float*)d_in[3];
  const float* W_dst = (const float*)d_in[4];
  const float* W_pos = (const float*)d_in[5];
  const float* b_pos = (const float*)d_in[6];
  const float* Wg    = (const float*)d_in[7];
  const float* bg    = (const float*)d_in[8];
  const float* W1    = (const float*)d_in[9];
  const float* b1    = (const float*)d_in[10];
  const float* W2    = (const float*)d_in[11];
  const float* b2    = (const float*)d_in[12];
  float* out = (float*)d_out;

  const size_t M = (size_t)BB * NN;        // 16384
  const size_t MC = M * CC;                // 2,097,152 floats

  // R6 workspace layout, verbatim (dedicated cand region, no aliasing)
  char* ws = (char*)d_ws;
  int* nbr = (int*)ws;                               // M*KMAX ints   = 2 MB
  unsigned short* cand = (unsigned short*)(ws + M * KMAX * sizeof(int));  // 8.4 MB
  float* fb = (float*)(ws + M * KMAX * sizeof(int) + M * CH * KMAX * sizeof(unsigned short));
  float* sb0 = fb + 0 * MC;
  float* sb1 = fb + 1 * MC;
  float* vb0 = fb + 2 * MC;
  float* vb1 = fb + 3 * MC;
  float* tb0 = fb + 4 * MC;
  float* tb1 = fb + 5 * MC;
  float* h   = fb + 6 * MC;
  float* g   = fb + 7 * MC;

  // 1. KNN with np-bit-exact f32 distance keys
  knn_p1<<<512, 256, 0, stream>>>(pos, cand);
  knn_p2<<<256, 64, 0, stream>>>(pos, cand, nbr);

  // 2. six projections fused in ONE launch (z: sb0,sb1,vb0,vb1,tb0,tb1)
  gemm_kernel<<<dim3(M / 64, 1, 6), 256, 0, stream>>>(
      x, CC, CC, nullptr, 0, CC, W_src, W_lin, W_dst, nullptr, fb, 0);

  // 3. h = leaky(concat(x,pos) @ Wg + bg)
  gemm_kernel<<<dim3(M / 64, 1, 1), 256, 0, stream>>>(
      x, CC, CC, pos, 3, CC + 3, Wg, nullptr, nullptr, bg, h, 1);

  // 4. h += attention, both dilations fused
  attn2_kernel<<<M, 128, 0, stream>>>(pos, nbr, sb0, vb0, tb0,
                                      sb1, vb1, tb1, W_pos, b_pos, h);

  // 5. g = leaky(h @ W1 + b1)
  gemm_kernel<<<dim3(M / 64, 1, 1), 256, 0, stream>>>(
      h, CC, CC, nullptr, 0, CC, W1, nullptr, nullptr, b1, g, 1);

  // 6. out = g @ W2 + b2 + pos
  final_kernel<<<M, 64, 0, stream>>>(g, W2, b2, pos, out);
}

// Round 8
// 415.985 us; speedup vs baseline: 1.2328x; 1.2328x over previous
//
#include <hip/hip_runtime.h>

#define BB 8
#define NN 2048
#define CC 128
#define KMAX 32
#define NEG 0.2f
#define CH 8
#define CHSZ (NN / CH)   // 256
#define CPAD 260         // chunk stride in LDS: (260*c+jj)%32 = (4c+jj)%32 -> 8 distinct banks
#define CAP 32           // per-thread candidate buffer (drain-on-full keeps j order)

// Map f32 to a u32 whose unsigned order == float order (handles negatives).
__device__ __forceinline__ unsigned int f2key(float f) {
  unsigned int b = __float_as_uint(f);
  return (b & 0x80000000u) ? ~b : (b | 0x80000000u);
}

// np-exact f32 squared norm: fl(fl(x^2+y^2)+z^2), no FMA contraction.
__device__ __forceinline__ float sq3(float x, float y, float z) {
  return __fadd_rn(__fadd_rn(__fmul_rn(x, x), __fmul_rn(y, y)), __fmul_rn(z, z));
}

// np-exact f32 distance key: d2 = fl( fl(sq_i+sq_j) - fl(2*dot) ),
// dot = fma(a2,b2, fma(a1,b1, round(a0*b0)))  (BLAS K-ascending FMA chain).
__device__ __forceinline__ float d2np(float px, float py, float pz, float sqq,
                                      float qx, float qy, float qz, float sqj) {
  float dot = __fmaf_rn(pz, qz, __fmaf_rn(py, qy, __fmul_rn(px, qx)));
  return __fsub_rn(__fadd_rn(sqq, sqj), __fmul_rn(2.0f, dot));
}

// ---------------------------------------------------------------------------
// K1a: KNN phase 1 — threshold-gated chunked selection, np-bit-exact keys.
// Pass A: keys-only top-4 per (query,chunk) -> T = max over chunks of 4th
//         smallest. 32 distinct candidates have key <= T, so T >= true 32nd
//         key: gate `key <= T` provably keeps every global-top-32 member
//         (ties at T included).
// Pass B: rescan; gate-passers buffered in j order (cheap predicated store),
//         then drained through the R7-verbatim stable depth-32 insert.
//         Overflow drains in place (order preserved). Result bit-identical
//         to R7's per-chunk top-32 lists restricted to keys <= T; dropped
//         entries (key > T) could never reach the final top-32. Empty slots
//         emit sentinel 0xFFFF (skipped in phase 2).
// Block = 256 threads = 32 queries x 8 chunks of one batch. Grid = 512.
// ---------------------------------------------------------------------------
__global__ __launch_bounds__(256) void knn_p1(const float* __restrict__ pos,
                                              unsigned short* __restrict__ cand) {
  __shared__ float spx[CH * CPAD], spy[CH * CPAD], spz[CH * CPAD], ssq[CH * CPAD];
  __shared__ unsigned int sred[256];
  __shared__ unsigned short sbuf[256 * CAP];
  int b = blockIdx.x >> 6;                       // 64 blocks per batch
  int qbase = (blockIdx.x & 63) * 32;
  const float* pb = pos + (size_t)b * NN * 3;
  for (int t = threadIdx.x; t < NN; t += 256) {
    int a = ((t >> 8) * CPAD) + (t & 255);       // padded SoA address of point t
    float x = pb[t * 3 + 0];
    float y = pb[t * 3 + 1];
    float z = pb[t * 3 + 2];
    spx[a] = x; spy[a] = y; spz[a] = z;
    ssq[a] = sq3(x, y, z);
  }
  __syncthreads();

  int q = qbase + (threadIdx.x >> 3);
  int c = threadIdx.x & 7;
  int qa = ((q >> 8) * CPAD) + (q & 255);
  float px = spx[qa], py = spy[qa], pz = spz[qa];
  float sqq = ssq[qa];

  int abase = c * CPAD;
  int j0 = c * CHSZ;

  // ---- Pass A: keys-only top-4 of this chunk (strict <, self-excluded) ----
  unsigned int a0 = 0xFFFFFFFFu, a1 = 0xFFFFFFFFu, a2 = 0xFFFFFFFFu, a3 = 0xFFFFFFFFu;
  for (int jj = 0; jj < CHSZ; ++jj) {
    int a = abase + jj;
    int j = j0 + jj;
    float d2 = d2np(px, py, pz, sqq, spx[a], spy[a], spz[a], ssq[a]);
    unsigned int key = f2key(d2);
    if (j == q) key = 0xFFFFFFFFu;
    if (key < a3) {
      bool c3 = key < a2;
      a3 = c3 ? a2 : key;
      bool c2 = key < a1;
      a2 = c3 ? (c2 ? a1 : key) : a2;
      bool c1 = key < a0;
      a1 = c2 ? (c1 ? a0 : key) : a1;
      a0 = c1 ? key : a0;
    }
  }
  sred[threadIdx.x] = a3;
  __syncthreads();
  if (c == 0) {
    unsigned int m = sred[threadIdx.x];
#pragma unroll
    for (int u = 1; u < 8; ++u) {
      unsigned int v = sred[threadIdx.x + u];
      m = v > m ? v : m;
    }
    sred[threadIdx.x] = m;
  }
  __syncthreads();
  unsigned int T = sred[threadIdx.x & ~7];

  // ---- Pass B: gate, buffer, drain through the exact R7 insert ----
  unsigned int ak[KMAX];
  int ai[KMAX];
#pragma unroll
  for (int k = 0; k < KMAX; ++k) { ak[k] = 0xFFFFFFFFu; ai[k] = 0xFFFF; }

  int sbase = threadIdx.x * CAP;
  auto drain = [&](int cnt2) {
    for (int u = 0; u < cnt2; ++u) {
      int jj2 = (int)sbuf[sbase + u];
      int a = abase + jj2;
      int j = j0 + jj2;
      float d2 = d2np(px, py, pz, sqq, spx[a], spy[a], spz[a], ssq[a]);
      unsigned int key = f2key(d2);               // self never buffered
      if (key < ak[KMAX - 1]) {                   // strict: stable ties -> lower j
#pragma unroll
        for (int k = KMAX - 1; k >= 1; --k) {
          bool ck  = key < ak[k];
          bool ckm = key < ak[k - 1];
          unsigned int tk = ckm ? ak[k - 1] : key;
          int          ti = ckm ? ai[k - 1] : j;
          ak[k] = ck ? tk : ak[k];
          ai[k] = ck ? ti : ai[k];
        }
        bool c0b = key < ak[0];
        ak[0] = c0b ? key : ak[0];
        ai[0] = c0b ? j : ai[0];
      }
    }
  };

  int cnt = 0;
  for (int jj = 0; jj < CHSZ; ++jj) {
    int a = abase + jj;
    int j = j0 + jj;
    float d2 = d2np(px, py, pz, sqq, spx[a], spy[a], spz[a], ssq[a]);
    unsigned int key = f2key(d2);
    if (j == q) key = 0xFFFFFFFFu;               // self fails gate (T < 0xFFFFFFFF)
    if (key <= T) {
      if (cnt == CAP) { drain(CAP); cnt = 0; }   // rare; preserves j order
      sbuf[sbase + cnt] = (unsigned short)jj;
      ++cnt;
    }
  }
  drain(cnt);

  unsigned short* oc = cand + (((size_t)(b * NN + q)) * CH + c) * KMAX;
#pragma unroll
  for (int k = 0; k < KMAX; ++k) oc[k] = (unsigned short)ai[k];
}

// ---------------------------------------------------------------------------
// K1b: KNN phase 2 — stable merge of the 8 chunk lists, same f32 keys.
// R6/R7 verbatim except sentinel entries (j = 0xFFFF) are skipped.
// ---------------------------------------------------------------------------
__global__ __launch_bounds__(64) void knn_p2(const float* __restrict__ pos,
                                             const unsigned short* __restrict__ cand,
                                             int* __restrict__ nbr) {
  __shared__ float sp[NN * 3];
  __shared__ float ssq[NN];
  int b = blockIdx.x >> 5;                       // 32 blocks per batch
  int q = (blockIdx.x & 31) * 64 + threadIdx.x;
  const float* pb = pos + (size_t)b * NN * 3;
  for (int t = threadIdx.x; t < NN * 3; t += 64) sp[t] = pb[t];
  __syncthreads();
  for (int t = threadIdx.x; t < NN; t += 64)
    ssq[t] = sq3(sp[t * 3 + 0], sp[t * 3 + 1], sp[t * 3 + 2]);
  __syncthreads();

  float px = sp[q * 3 + 0], py = sp[q * 3 + 1], pz = sp[q * 3 + 2];
  float sqq = ssq[q];

  unsigned int ak[KMAX];
  int ai[KMAX];
#pragma unroll
  for (int k = 0; k < KMAX; ++k) { ak[k] = 0xFFFFFFFFu; ai[k] = 0; }

  const unsigned short* cq = cand + ((size_t)(b * NN + q)) * (CH * KMAX);
  for (int u = 0; u < CH * KMAX; ++u) {
    int j = (int)cq[u];
    unsigned int key;
    if (j < NN) {
      float d2 = d2np(px, py, pz, sqq,
                      sp[j * 3 + 0], sp[j * 3 + 1], sp[j * 3 + 2], ssq[j]);
      key = f2key(d2);
      if (j == q) key = 0xFFFFFFFFu;
    } else {
      key = 0xFFFFFFFFu;                         // sentinel slot: never inserted
    }
    if (key < ak[KMAX - 1]) {
#pragma unroll
      for (int k = KMAX - 1; k >= 1; --k) {
        bool ck  = key < ak[k];
        bool ckm = key < ak[k - 1];
        unsigned int tk = ckm ? ak[k - 1] : key;
        int          ti = ckm ? ai[k - 1] : j;
        ak[k] = ck ? tk : ak[k];
        ai[k] = ck ? ti : ai[k];
      }
      bool c0 = key < ak[0];
      ak[0] = c0 ? key : ak[0];
      ai[0] = c0 ? j : ai[0];
    }
  }

  int* onb = nbr + ((size_t)(b * NN + q)) * KMAX;
#pragma unroll
  for (int k = 0; k < KMAX; ++k) onb[k] = ai[k];
}

// ---------------------------------------------------------------------------
// K2: f32 tiled GEMM  out[M][128] = concat(A1[:,0:K1], A2[:,0:K-K1]) @ W
// blockIdx.z selects among up to 6 weight matrices and output slices.
// (verbatim from the R7 passing kernel)
// ---------------------------------------------------------------------------
__global__ __launch_bounds__(256) void gemm_kernel(
    const float* __restrict__ A1, int lda1, int K1,
    const float* __restrict__ A2, int lda2, int K,
    const float* __restrict__ Wa, const float* __restrict__ Wb,
    const float* __restrict__ Wc, const float* __restrict__ bias,
    float* __restrict__ outbase, int applyLeaky) {
  __shared__ float At[8][64];
  __shared__ float Wt[8][CC];

  int z = blockIdx.z;
  const float* W = (z < 2) ? (Wa + (size_t)z * CC * CC)
                 : (z < 4) ? (Wb + (size_t)(z - 2) * CC * CC)
                           : (Wc + (size_t)(z - 4) * CC * CC);
  float* out = outbase + (size_t)z * ((size_t)BB * NN * CC);

  int m0 = blockIdx.x * 64;
  int tid = threadIdx.x;
  int cg = tid & 31;
  int rg = tid >> 5;

  float acc[8][4];
#pragma unroll
  for (int r = 0; r < 8; ++r)
#pragma unroll
    for (int q = 0; q < 4; ++q) acc[r][q] = 0.f;

  int ksteps = (K + 7) >> 3;
  for (int ks = 0; ks < ksteps; ++ks) {
    int k0 = ks << 3;
    __syncthreads();
    {
      int f = tid * 2;
      int m = f >> 3;
      int kk = f & 7;
      int gm = m0 + m;
#pragma unroll
      for (int u = 0; u < 2; ++u) {
        int k = k0 + kk + u;
        float v = 0.f;
        if (k < K1) v = A1[(size_t)gm * lda1 + k];
        else if (k < K) v = A2[(size_t)gm * lda2 + (k - K1)];
        At[kk + u][m] = v;
      }
    }
    {
      int kk = tid >> 5;
      int c = (tid & 31) * 4;
      int k = k0 + kk;
      float4 w = make_float4(0.f, 0.f, 0.f, 0.f);
      if (k < K) w = *(const float4*)(W + (size_t)k * CC + c);
      *(float4*)(&Wt[kk][c]) = w;
    }
    __syncthreads();
#pragma unroll
    for (int kk = 0; kk < 8; ++kk) {
      float4 a0 = *(const float4*)(&At[kk][rg * 8]);
      float4 a1 = *(const float4*)(&At[kk][rg * 8 + 4]);
      float4 w = *(const float4*)(&Wt[kk][cg * 4]);
      float a[8] = {a0.x, a0.y, a0.z, a0.w, a1.x, a1.y, a1.z, a1.w};
#pragma unroll
      for (int r = 0; r < 8; ++r) {
        acc[r][0] += a[r] * w.x;
        acc[r][1] += a[r] * w.y;
        acc[r][2] += a[r] * w.z;
        acc[r][3] += a[r] * w.w;
      }
    }
  }

#pragma unroll
  for (int r = 0; r < 8; ++r) {
    int m = m0 + rg * 8 + r;
#pragma unroll
    for (int q = 0; q < 4; ++q) {
      int c = cg * 4 + q;
      float v = acc[r][q];
      if (bias) v += bias[c];
      if (applyLeaky) v = v > 0.f ? v : NEG * v;
      out[(size_t)m * CC + c] = v;
    }
  }
}

// ---------------------------------------------------------------------------
// K3: fused attention — both dilations in one launch, one h read/write.
// (verbatim from the R7 passing kernel)
// ---------------------------------------------------------------------------
__global__ __launch_bounds__(128) void attn2_kernel(
    const float* __restrict__ pos, const int* __restrict__ nbr,
    const float* __restrict__ s0, const float* __restrict__ v0,
    const float* __restrict__ t0,
    const float* __restrict__ s1, const float* __restrict__ v1,
    const float* __restrict__ t1,
    const float* __restrict__ Wpos, const float* __restrict__ bpos,
    float* __restrict__ h) {
  int bn = blockIdx.x;
  int b = bn >> 11;
  int n = bn & (NN - 1);
  int c = threadIdx.x;

  const float* pb = pos + (size_t)b * NN * 3;
  float pix = pb[n * 3 + 0], piy = pb[n * 3 + 1], piz = pb[n * 3 + 2];
  const int* nb = nbr + (size_t)bn * KMAX;

  float ht = h[(size_t)bn * CC + c];             // h_in (Wg output)

#pragma unroll
  for (int l = 0; l < 2; ++l) {
    int dil = l + 1;
    const float* s = l ? s1 : s0;
    const float* v = l ? v1 : v0;
    const float* t = l ? t1 : t0;
    const float* Wp = Wpos + (size_t)l * 3 * CC;
    float w0 = Wp[c], w1 = Wp[CC + c], w2 = Wp[2 * CC + c];
    float bp = bpos[(size_t)l * CC + c];
    float tc = t[(size_t)bn * CC + c];

    float alpha[17], del[17];
    float mx = -1e30f;
#pragma unroll
    for (int j = 0; j < 17; ++j) {
      int idx = (j < 16) ? nb[j * dil] : n;
      float dx = pix - pb[idx * 3 + 0];
      float dy = piy - pb[idx * 3 + 1];
      float dz = piz - pb[idx * 3 + 2];
      float d = dx * w0 + dy * w1 + dz * w2 + bp;
      del[j] = d;
      float sc = s[((size_t)(b * NN + idx)) * CC + c];
      float a = tc - sc + d;
      alpha[j] = a;
      mx = fmaxf(mx, a);
    }
    float sum = 0.f;
#pragma unroll
    for (int j = 0; j < 17; ++j) {
      float w = expf(alpha[j] - mx);
      alpha[j] = w;
      sum += w;
    }
    float inv = 1.f / sum;
    float hc = 0.f;
#pragma unroll
    for (int j = 0; j < 17; ++j) {
      int idx = (j < 16) ? nb[j * dil] : n;
      float vc = v[((size_t)(b * NN + idx)) * CC + c];
      hc += alpha[j] * (vc + del[j]);
    }
    ht += hc * inv;
  }

  h[(size_t)bn * CC + c] = ht;
}

// ---------------------------------------------------------------------------
// K5: out[m][0..2] = g[m] @ W2 + b2 + pos[m].  One wave per point.
// (verbatim from the R7 passing kernel)
// ---------------------------------------------------------------------------
__global__ __launch_bounds__(64) void final_kernel(
    const float* __restrict__ g, const float* __restrict__ W2,
    const float* __restrict__ b2, const float* __restrict__ pos,
    float* __restrict__ out) {
  int m = blockIdx.x;
  int k = threadIdx.x;
  float g0 = g[(size_t)m * CC + k];
  float g1 = g[(size_t)m * CC + 64 + k];
  float p0 = g0 * W2[k * 3 + 0] + g1 * W2[(k + 64) * 3 + 0];
  float p1 = g0 * W2[k * 3 + 1] + g1 * W2[(k + 64) * 3 + 1];
  float p2 = g0 * W2[k * 3 + 2] + g1 * W2[(k + 64) * 3 + 2];
#pragma unroll
  for (int off = 32; off >= 1; off >>= 1) {
    p0 += __shfl_down(p0, off);
    p1 += __shfl_down(p1, off);
    p2 += __shfl_down(p2, off);
  }
  if (k == 0) {
    out[m * 3 + 0] = p0 + b2[0] + pos[m * 3 + 0];
    out[m * 3 + 1] = p1 + b2[1] + pos[m * 3 + 1];
    out[m * 3 + 2] = p2 + b2[2] + pos[m * 3 + 2];
  }
}

extern "C" void kernel_launch(void* const* d_in, const int* in_sizes, int n_in,
                              void* d_out, int out_size, void* d_ws, size_t ws_size,
                              hipStream_t stream) {
  const float* x     = (const float*)d_in[0];
  const float* pos   = (const float*)d_in[1];
  const float* W_lin = (const float*)d_in[2];
  const float* W_src = (const float*)d_in[3];
  const float* W_dst = (const float*)d_in[4];
  const float* W_pos = (const float*)d_in[5];
  const float* b_pos = (const float*)d_in[6];
  const float* Wg    = (const float*)d_in[7];
  const float* bg    = (const float*)d_in[8];
  const float* W1    = (const float*)d_in[9];
  const float* b1    = (const float*)d_in[10];
  const float* W2    = (const float*)d_in[11];
  const float* b2    = (const float*)d_in[12];
  float* out = (float*)d_out;

  const size_t M = (size_t)BB * NN;        // 16384
  const size_t MC = M * CC;                // 2,097,152 floats

  // R7 workspace layout, verbatim (dedicated cand region, no aliasing)
  char* ws = (char*)d_ws;
  int* nbr = (int*)ws;                               // M*KMAX ints   = 2 MB
  unsigned short* cand = (unsigned short*)(ws + M * KMAX * sizeof(int));  // 8.4 MB
  float* fb = (float*)(ws + M * KMAX * sizeof(int) + M * CH * KMAX * sizeof(unsigned short));
  float* sb0 = fb + 0 * MC;
  float* sb1 = fb + 1 * MC;
  float* vb0 = fb + 2 * MC;
  float* vb1 = fb + 3 * MC;
  float* tb0 = fb + 4 * MC;
  float* tb1 = fb + 5 * MC;
  float* h   = fb + 6 * MC;
  float* g   = fb + 7 * MC;

  // 1. KNN with np-bit-exact f32 distance keys
  knn_p1<<<512, 256, 0, stream>>>(pos, cand);
  knn_p2<<<256, 64, 0, stream>>>(pos, cand, nbr);

  // 2. six projections fused in ONE launch (z: sb0,sb1,vb0,vb1,tb0,tb1)
  gemm_kernel<<<dim3(M / 64, 1, 6), 256, 0, stream>>>(
      x, CC, CC, nullptr, 0, CC, W_src, W_lin, W_dst, nullptr, fb, 0);

  // 3. h = leaky(concat(x,pos) @ Wg + bg)
  gemm_kernel<<<dim3(M / 64, 1, 1), 256, 0, stream>>>(
      x, CC, CC, pos, 3, CC + 3, Wg, nullptr, nullptr, bg, h, 1);

  // 4. h += attention, both dilations fused
  attn2_kernel<<<M, 128, 0, stream>>>(pos, nbr, sb0, vb0, tb0,
                                      sb1, vb1, tb1, W_pos, b_pos, h);

  // 5. g = leaky(h @ W1 + b1)
  gemm_kernel<<<dim3(M / 64, 1, 1), 256, 0, stream>>>(
      h, CC, CC, nullptr, 0, CC, W1, nullptr, nullptr, b1, g, 1);

  // 6. out = g @ W2 + b2 + pos
  final_kernel<<<M, 64, 0, stream>>>(g, W2, b2, pos, out);
}

// Round 9
// 360.652 us; speedup vs baseline: 1.4220x; 1.1534x over previous
//
#include <hip/hip_runtime.h>

#define BB 8
#define NN 2048
#define CC 128
#define KMAX 32
#define NEG 0.2f
#define CH 8
#define CHSZ (NN / CH)   // 256
#define CPAD 260         // chunk stride in LDS: (260*c+jj)%32 = (4c+jj)%32 -> 8 distinct banks
#define CAP 32           // per-thread candidate buffer (drain-on-full keeps j order)

// Map f32 to a u32 whose unsigned order == float order (handles negatives).
__device__ __forceinline__ unsigned int f2key(float f) {
  unsigned int b = __float_as_uint(f);
  return (b & 0x80000000u) ? ~b : (b | 0x80000000u);
}

// np-exact f32 squared norm: fl(fl(x^2+y^2)+z^2), no FMA contraction.
__device__ __forceinline__ float sq3(float x, float y, float z) {
  return __fadd_rn(__fadd_rn(__fmul_rn(x, x), __fmul_rn(y, y)), __fmul_rn(z, z));
}

// np-exact f32 distance key: d2 = fl( fl(sq_i+sq_j) - fl(2*dot) ),
// dot = fma(a2,b2, fma(a1,b1, round(a0*b0)))  (BLAS K-ascending FMA chain).
__device__ __forceinline__ float d2np(float px, float py, float pz, float sqq,
                                      float qx, float qy, float qz, float sqj) {
  float dot = __fmaf_rn(pz, qz, __fmaf_rn(py, qy, __fmul_rn(px, qx)));
  return __fsub_rn(__fadd_rn(sqq, sqj), __fmul_rn(2.0f, dot));
}

// ---------------------------------------------------------------------------
// K1a: KNN phase 1 — threshold-gated chunked selection, np-bit-exact keys.
// Selection logic VERBATIM from the passing R8 kernel. Only addition: the
// sorted key array ak[] is emitted alongside ai[] so phase 2 can merge
// without recomputing distances.
// Block = 256 threads = 32 queries x 8 chunks of one batch. Grid = 512.
// ---------------------------------------------------------------------------
__global__ __launch_bounds__(256) void knn_p1(const float* __restrict__ pos,
                                              unsigned short* __restrict__ cand,
                                              unsigned int* __restrict__ candk) {
  __shared__ float spx[CH * CPAD], spy[CH * CPAD], spz[CH * CPAD], ssq[CH * CPAD];
  __shared__ unsigned int sred[256];
  __shared__ unsigned short sbuf[256 * CAP];
  int b = blockIdx.x >> 6;                       // 64 blocks per batch
  int qbase = (blockIdx.x & 63) * 32;
  const float* pb = pos + (size_t)b * NN * 3;
  for (int t = threadIdx.x; t < NN; t += 256) {
    int a = ((t >> 8) * CPAD) + (t & 255);       // padded SoA address of point t
    float x = pb[t * 3 + 0];
    float y = pb[t * 3 + 1];
    float z = pb[t * 3 + 2];
    spx[a] = x; spy[a] = y; spz[a] = z;
    ssq[a] = sq3(x, y, z);
  }
  __syncthreads();

  int q = qbase + (threadIdx.x >> 3);
  int c = threadIdx.x & 7;
  int qa = ((q >> 8) * CPAD) + (q & 255);
  float px = spx[qa], py = spy[qa], pz = spz[qa];
  float sqq = ssq[qa];

  int abase = c * CPAD;
  int j0 = c * CHSZ;

  // ---- Pass A: keys-only top-4 of this chunk (strict <, self-excluded) ----
  unsigned int a0 = 0xFFFFFFFFu, a1 = 0xFFFFFFFFu, a2 = 0xFFFFFFFFu, a3 = 0xFFFFFFFFu;
  for (int jj = 0; jj < CHSZ; ++jj) {
    int a = abase + jj;
    int j = j0 + jj;
    float d2 = d2np(px, py, pz, sqq, spx[a], spy[a], spz[a], ssq[a]);
    unsigned int key = f2key(d2);
    if (j == q) key = 0xFFFFFFFFu;
    if (key < a3) {
      bool c3 = key < a2;
      a3 = c3 ? a2 : key;
      bool c2 = key < a1;
      a2 = c3 ? (c2 ? a1 : key) : a2;
      bool c1 = key < a0;
      a1 = c2 ? (c1 ? a0 : key) : a1;
      a0 = c1 ? key : a0;
    }
  }
  sred[threadIdx.x] = a3;
  __syncthreads();
  if (c == 0) {
    unsigned int m = sred[threadIdx.x];
#pragma unroll
    for (int u = 1; u < 8; ++u) {
      unsigned int v = sred[threadIdx.x + u];
      m = v > m ? v : m;
    }
    sred[threadIdx.x] = m;
  }
  __syncthreads();
  unsigned int T = sred[threadIdx.x & ~7];

  // ---- Pass B: gate, buffer, drain through the exact R7 insert ----
  unsigned int ak[KMAX];
  int ai[KMAX];
#pragma unroll
  for (int k = 0; k < KMAX; ++k) { ak[k] = 0xFFFFFFFFu; ai[k] = 0xFFFF; }

  int sbase = threadIdx.x * CAP;
  auto drain = [&](int cnt2) {
    for (int u = 0; u < cnt2; ++u) {
      int jj2 = (int)sbuf[sbase + u];
      int a = abase + jj2;
      int j = j0 + jj2;
      float d2 = d2np(px, py, pz, sqq, spx[a], spy[a], spz[a], ssq[a]);
      unsigned int key = f2key(d2);               // self never buffered
      if (key < ak[KMAX - 1]) {                   // strict: stable ties -> lower j
#pragma unroll
        for (int k = KMAX - 1; k >= 1; --k) {
          bool ck  = key < ak[k];
          bool ckm = key < ak[k - 1];
          unsigned int tk = ckm ? ak[k - 1] : key;
          int          ti = ckm ? ai[k - 1] : j;
          ak[k] = ck ? tk : ak[k];
          ai[k] = ck ? ti : ai[k];
        }
        bool c0b = key < ak[0];
        ak[0] = c0b ? key : ak[0];
        ai[0] = c0b ? j : ai[0];
      }
    }
  };

  int cnt = 0;
  for (int jj = 0; jj < CHSZ; ++jj) {
    int a = abase + jj;
    int j = j0 + jj;
    float d2 = d2np(px, py, pz, sqq, spx[a], spy[a], spz[a], ssq[a]);
    unsigned int key = f2key(d2);
    if (j == q) key = 0xFFFFFFFFu;               // self fails gate (T < 0xFFFFFFFF)
    if (key <= T) {
      if (cnt == CAP) { drain(CAP); cnt = 0; }   // rare; preserves j order
      sbuf[sbase + cnt] = (unsigned short)jj;
      ++cnt;
    }
  }
  drain(cnt);

  size_t obase = (((size_t)(b * NN + q)) * CH + c) * KMAX;
  unsigned short* oc = cand + obase;
  unsigned int* ok = candk + obase;
#pragma unroll
  for (int k = 0; k < KMAX; ++k) {
    oc[k] = (unsigned short)ai[k];
    ok[k] = ak[k];
  }
}

// ---------------------------------------------------------------------------
// K1b: KNN phase 2 — 8-way merge of the stable-sorted chunk lists.
// Lists are sorted (key asc, j asc) and chunks are j-contiguous ascending,
// so strict-< argmin scanning c=0..7 reproduces exactly the (key, lower-j)
// stable rule -> nbr bit-identical to the R8 recompute version. Sentinel
// slots (key 0xFFFFFFFF) never win while >=32 real entries exist (guaranteed
// by the gate). One thread per query; ~640 VALU ops + ~40 L2 loads.
// ---------------------------------------------------------------------------
__global__ __launch_bounds__(64) void knn_p2(const unsigned int* __restrict__ candk,
                                             const unsigned short* __restrict__ cand,
                                             int* __restrict__ nbr) {
  int q = blockIdx.x * 64 + threadIdx.x;         // global query id (b*NN+n)
  const unsigned int* k8 = candk + (size_t)q * (CH * KMAX);
  const unsigned short* i8 = cand + (size_t)q * (CH * KMAX);

  int head[CH];
  unsigned int hk[CH];
#pragma unroll
  for (int c = 0; c < CH; ++c) {
    head[c] = 0;
    hk[c] = k8[c * KMAX];
  }

  int* onb = nbr + (size_t)q * KMAX;
#pragma unroll
  for (int r = 0; r < KMAX; ++r) {
    int bc = 0;
    unsigned int bk = hk[0];
#pragma unroll
    for (int c = 1; c < CH; ++c) {
      if (hk[c] < bk) { bk = hk[c]; bc = c; }    // strict: ties -> lower c = lower j
    }
    onb[r] = (int)i8[bc * KMAX + head[bc]];
    ++head[bc];
    hk[bc] = (head[bc] < KMAX) ? k8[bc * KMAX + head[bc]] : 0xFFFFFFFFu;
  }
}

// ---------------------------------------------------------------------------
// K2: f32 tiled GEMM  out[M][128] = concat(A1[:,0:K1], A2[:,0:K-K1]) @ W
// blockIdx.z selects among up to 6 weight matrices and output slices.
// (verbatim from the R8 passing kernel)
// ---------------------------------------------------------------------------
__global__ __launch_bounds__(256) void gemm_kernel(
    const float* __restrict__ A1, int lda1, int K1,
    const float* __restrict__ A2, int lda2, int K,
    const float* __restrict__ Wa, const float* __restrict__ Wb,
    const float* __restrict__ Wc, const float* __restrict__ bias,
    float* __restrict__ outbase, int applyLeaky) {
  __shared__ float At[8][64];
  __shared__ float Wt[8][CC];

  int z = blockIdx.z;
  const float* W = (z < 2) ? (Wa + (size_t)z * CC * CC)
                 : (z < 4) ? (Wb + (size_t)(z - 2) * CC * CC)
                           : (Wc + (size_t)(z - 4) * CC * CC);
  float* out = outbase + (size_t)z * ((size_t)BB * NN * CC);

  int m0 = blockIdx.x * 64;
  int tid = threadIdx.x;
  int cg = tid & 31;
  int rg = tid >> 5;

  float acc[8][4];
#pragma unroll
  for (int r = 0; r < 8; ++r)
#pragma unroll
    for (int q = 0; q < 4; ++q) acc[r][q] = 0.f;

  int ksteps = (K + 7) >> 3;
  for (int ks = 0; ks < ksteps; ++ks) {
    int k0 = ks << 3;
    __syncthreads();
    {
      int f = tid * 2;
      int m = f >> 3;
      int kk = f & 7;
      int gm = m0 + m;
#pragma unroll
      for (int u = 0; u < 2; ++u) {
        int k = k0 + kk + u;
        float v = 0.f;
        if (k < K1) v = A1[(size_t)gm * lda1 + k];
        else if (k < K) v = A2[(size_t)gm * lda2 + (k - K1)];
        At[kk + u][m] = v;
      }
    }
    {
      int kk = tid >> 5;
      int c = (tid & 31) * 4;
      int k = k0 + kk;
      float4 w = make_float4(0.f, 0.f, 0.f, 0.f);
      if (k < K) w = *(const float4*)(W + (size_t)k * CC + c);
      *(float4*)(&Wt[kk][c]) = w;
    }
    __syncthreads();
#pragma unroll
    for (int kk = 0; kk < 8; ++kk) {
      float4 a0 = *(const float4*)(&At[kk][rg * 8]);
      float4 a1 = *(const float4*)(&At[kk][rg * 8 + 4]);
      float4 w = *(const float4*)(&Wt[kk][cg * 4]);
      float a[8] = {a0.x, a0.y, a0.z, a0.w, a1.x, a1.y, a1.z, a1.w};
#pragma unroll
      for (int r = 0; r < 8; ++r) {
        acc[r][0] += a[r] * w.x;
        acc[r][1] += a[r] * w.y;
        acc[r][2] += a[r] * w.z;
        acc[r][3] += a[r] * w.w;
      }
    }
  }

#pragma unroll
  for (int r = 0; r < 8; ++r) {
    int m = m0 + rg * 8 + r;
#pragma unroll
    for (int q = 0; q < 4; ++q) {
      int c = cg * 4 + q;
      float v = acc[r][q];
      if (bias) v += bias[c];
      if (applyLeaky) v = v > 0.f ? v : NEG * v;
      out[(size_t)m * CC + c] = v;
    }
  }
}

// ---------------------------------------------------------------------------
// K3: fused attention — both dilations in one launch, one h read/write.
// (verbatim from the R8 passing kernel)
// ---------------------------------------------------------------------------
__global__ __launch_bounds__(128) void attn2_kernel(
    const float* __restrict__ pos, const int* __restrict__ nbr,
    const float* __restrict__ s0, const float* __restrict__ v0,
    const float* __restrict__ t0,
    const float* __restrict__ s1, const float* __restrict__ v1,
    const float* __restrict__ t1,
    const float* __restrict__ Wpos, const float* __restrict__ bpos,
    float* __restrict__ h) {
  int bn = blockIdx.x;
  int b = bn >> 11;
  int n = bn & (NN - 1);
  int c = threadIdx.x;

  const float* pb = pos + (size_t)b * NN * 3;
  float pix = pb[n * 3 + 0], piy = pb[n * 3 + 1], piz = pb[n * 3 + 2];
  const int* nb = nbr + (size_t)bn * KMAX;

  float ht = h[(size_t)bn * CC + c];             // h_in (Wg output)

#pragma unroll
  for (int l = 0; l < 2; ++l) {
    int dil = l + 1;
    const float* s = l ? s1 : s0;
    const float* v = l ? v1 : v0;
    const float* t = l ? t1 : t0;
    const float* Wp = Wpos + (size_t)l * 3 * CC;
    float w0 = Wp[c], w1 = Wp[CC + c], w2 = Wp[2 * CC + c];
    float bp = bpos[(size_t)l * CC + c];
    float tc = t[(size_t)bn * CC + c];

    float alpha[17], del[17];
    float mx = -1e30f;
#pragma unroll
    for (int j = 0; j < 17; ++j) {
      int idx = (j < 16) ? nb[j * dil] : n;
      float dx = pix - pb[idx * 3 + 0];
      float dy = piy - pb[idx * 3 + 1];
      float dz = piz - pb[idx * 3 + 2];
      float d = dx * w0 + dy * w1 + dz * w2 + bp;
      del[j] = d;
      float sc = s[((size_t)(b * NN + idx)) * CC + c];
      float a = tc - sc + d;
      alpha[j] = a;
      mx = fmaxf(mx, a);
    }
    float sum = 0.f;
#pragma unroll
    for (int j = 0; j < 17; ++j) {
      float w = expf(alpha[j] - mx);
      alpha[j] = w;
      sum += w;
    }
    float inv = 1.f / sum;
    float hc = 0.f;
#pragma unroll
    for (int j = 0; j < 17; ++j) {
      int idx = (j < 16) ? nb[j * dil] : n;
      float vc = v[((size_t)(b * NN + idx)) * CC + c];
      hc += alpha[j] * (vc + del[j]);
    }
    ht += hc * inv;
  }

  h[(size_t)bn * CC + c] = ht;
}

// ---------------------------------------------------------------------------
// K5: out[m][0..2] = g[m] @ W2 + b2 + pos[m].  One wave per point.
// (verbatim from the R8 passing kernel)
// ---------------------------------------------------------------------------
__global__ __launch_bounds__(64) void final_kernel(
    const float* __restrict__ g, const float* __restrict__ W2,
    const float* __restrict__ b2, const float* __restrict__ pos,
    float* __restrict__ out) {
  int m = blockIdx.x;
  int k = threadIdx.x;
  float g0 = g[(size_t)m * CC + k];
  float g1 = g[(size_t)m * CC + 64 + k];
  float p0 = g0 * W2[k * 3 + 0] + g1 * W2[(k + 64) * 3 + 0];
  float p1 = g0 * W2[k * 3 + 1] + g1 * W2[(k + 64) * 3 + 1];
  float p2 = g0 * W2[k * 3 + 2] + g1 * W2[(k + 64) * 3 + 2];
#pragma unroll
  for (int off = 32; off >= 1; off >>= 1) {
    p0 += __shfl_down(p0, off);
    p1 += __shfl_down(p1, off);
    p2 += __shfl_down(p2, off);
  }
  if (k == 0) {
    out[m * 3 + 0] = p0 + b2[0] + pos[m * 3 + 0];
    out[m * 3 + 1] = p1 + b2[1] + pos[m * 3 + 1];
    out[m * 3 + 2] = p2 + b2[2] + pos[m * 3 + 2];
  }
}

extern "C" void kernel_launch(void* const* d_in, const int* in_sizes, int n_in,
                              void* d_out, int out_size, void* d_ws, size_t ws_size,
                              hipStream_t stream) {
  const float* x     = (const float*)d_in[0];
  const float* pos   = (const float*)d_in[1];
  const float* W_lin = (const float*)d_in[2];
  const float* W_src = (const float*)d_in[3];
  const float* W_dst = (const float*)d_in[4];
  const float* W_pos = (const float*)d_in[5];
  const float* b_pos = (const float*)d_in[6];
  const float* Wg    = (const float*)d_in[7];
  const float* bg    = (const float*)d_in[8];
  const float* W1    = (const float*)d_in[9];
  const float* b1    = (const float*)d_in[10];
  const float* W2    = (const float*)d_in[11];
  const float* b2    = (const float*)d_in[12];
  float* out = (float*)d_out;

  const size_t M = (size_t)BB * NN;        // 16384
  const size_t MC = M * CC;                // 2,097,152 floats

  char* ws = (char*)d_ws;
  int* nbr = (int*)ws;                               // M*KMAX ints   = 2 MB
  unsigned short* cand = (unsigned short*)(ws + M * KMAX * sizeof(int));  // 8.4 MB
  float* fb = (float*)(ws + M * KMAX * sizeof(int) + M * CH * KMAX * sizeof(unsigned short));
  float* sb0 = fb + 0 * MC;
  float* sb1 = fb + 1 * MC;
  float* vb0 = fb + 2 * MC;
  float* vb1 = fb + 3 * MC;
  float* tb0 = fb + 4 * MC;
  float* tb1 = fb + 5 * MC;
  float* h   = fb + 6 * MC;
  float* g   = fb + 7 * MC;
  // candk (u32, M*CH*KMAX = 16.78 MB) aliases h+g (exactly 2*MC floats):
  // dead before the Wg GEMM writes h (stream-ordered after knn_p2).
  unsigned int* candk = (unsigned int*)h;

  // 1. KNN: gated chunk selection, then 8-way sorted merge (bit-identical)
  knn_p1<<<512, 256, 0, stream>>>(pos, cand, candk);
  knn_p2<<<256, 64, 0, stream>>>(candk, cand, nbr);

  // 2. six projections fused in ONE launch (z: sb0,sb1,vb0,vb1,tb0,tb1)
  gemm_kernel<<<dim3(M / 64, 1, 6), 256, 0, stream>>>(
      x, CC, CC, nullptr, 0, CC, W_src, W_lin, W_dst, nullptr, fb, 0);

  // 3. h = leaky(concat(x,pos) @ Wg + bg)
  gemm_kernel<<<dim3(M / 64, 1, 1), 256, 0, stream>>>(
      x, CC, CC, pos, 3, CC + 3, Wg, nullptr, nullptr, bg, h, 1);

  // 4. h += attention, both dilations fused
  attn2_kernel<<<M, 128, 0, stream>>>(pos, nbr, sb0, vb0, tb0,
                                      sb1, vb1, tb1, W_pos, b_pos, h);

  // 5. g = leaky(h @ W1 + b1)
  gemm_kernel<<<dim3(M / 64, 1, 1), 256, 0, stream>>>(
      h, CC, CC, nullptr, 0, CC, W1, nullptr, nullptr, b1, g, 1);

  // 6. out = g @ W2 + b2 + pos
  final_kernel<<<M, 64, 0, stream>>>(g, W2, b2, pos, out);
}